// Round 6
// baseline (103.683 us; speedup 1.0000x reference)
//
#include <hip/hip_runtime.h>

namespace {
constexpr int H = 480, W = 640, B = 32;
constexpr int HW = H * W;
constexpr float CXf = 313.04f, CYf = 238.44f;
// XLA algebraic-simplifier style: divide-by-constant -> multiply-by-f32-reciprocal
constexpr float RCPX = 1.0f / 582.62f;
constexpr float RCPY = 1.0f / 582.69f;
}

// Exact IEEE f32 mul/add, contraction-proof (inline asm is opaque to FMA fusion).
__device__ __forceinline__ float fmul_ieee(float a, float b) {
    float r;
    asm("v_mul_f32 %0, %1, %2" : "=v"(r) : "v"(a), "v"(b));
    return r;
}
__device__ __forceinline__ float fadd_ieee(float a, float b) {
    float r;
    asm("v_add_f32 %0, %1, %2" : "=v"(r) : "v"(a), "v"(b));
    return r;
}

// ((A*n0) + (B*n1)) + n2  -- sequential f32 sum order, no FMA anywhere.
__device__ __forceinline__ float abc_dot(float A, float Bv, float a0, float a1, float a2) {
    return fadd_ieee(fadd_ieee(fmul_ieee(A, a0), fmul_ieee(Bv, a1)), a2);
}

// Grid coordinate: fl32(i - C) then multiply by f32 reciprocal (XLA div->mul).
__device__ __forceinline__ float gx(int i) {
    float t = (float)i - CXf;      // exact int, one f32 rounding on subtract
    return fmul_ieee(t, RCPX);
}
__device__ __forceinline__ float gy(int i) {
    float t = (float)i - CYf;
    return fmul_ieee(t, RCPY);
}

__global__ __launch_bounds__(256) void znext_kernel(
    const float* __restrict__ depth,
    const float* __restrict__ normal,
    float* __restrict__ out)
{
    int idx = blockIdx.x * blockDim.x + threadIdx.x;
    if (idx >= B * HW) return;
    int b = idx / HW;
    int p = idx - b * HW;
    int y = p / W;
    int x = p - y * W;

    const float* d  = depth + (size_t)b * HW;
    const float* n0 = normal + (size_t)b * 3 * HW;
    const float* n1 = n0 + HW;
    const float* n2 = n1 + HW;
    float* o = out + (size_t)b * 4 * HW + p;

    // Own-pixel grid coords (all denominators use these)
    float Ax = gx(x);
    float By = gy(y);

    // ---- z_o_up[y][x] = safe_div(ABC_down, ABC_up)(y+1,x) * depth[y+2][x]
    float zu = 0.0f;
    if (y < H - 2) {
        int q = p + W;
        float a0 = n0[q], a1 = n1[q], a2 = n2[q];
        float Bnum = gy(y + 2);                      // abc(0,+1) B-grid at row y+1
        float num = abc_dot(Ax, Bnum, a0, a1, a2);   // ABC_down(y+1,x)
        float den = abc_dot(Ax, By,   a0, a1, a2);   // ABC_up(y+1,x)
        if (den != 0.0f) zu = (num / den) * d[p + 2 * W];
    }

    // ---- z_o_down[y][x] = safe_div(ABC_up, ABC_down)(y-1,x) * depth[y-2][x]
    float zd = 0.0f;
    if (y >= 2) {
        int q = p - W;
        float a0 = n0[q], a1 = n1[q], a2 = n2[q];
        float Bnum = gy(y - 2);                      // abc(0,-1) B-grid at row y-1
        float num = abc_dot(Ax, Bnum, a0, a1, a2);   // ABC_up(y-1,x)
        float den = abc_dot(Ax, By,   a0, a1, a2);   // ABC_down(y-1,x)
        if (den != 0.0f) zd = (num / den) * d[p - 2 * W];
    }

    // ---- z_o_left[y][x] = safe_div(ABC_right, ABC_left)(y,x+1) * depth[y][x+2]
    float zl = 0.0f;
    if (x < W - 2) {
        int q = p + 1;
        float a0 = n0[q], a1 = n1[q], a2 = n2[q];
        float Anum = gx(x + 2);                      // abc(+1,0) A-grid at col x+1
        float num = abc_dot(Anum, By, a0, a1, a2);   // ABC_right(y,x+1)
        float den = abc_dot(Ax,   By, a0, a1, a2);   // ABC_left(y,x+1)
        if (den != 0.0f) zl = (num / den) * d[p + 2];
    }

    // ---- z_o_right[y][x] = safe_div(ABC_left, ABC_right)(y,x-1) * depth[y][x-2]
    float zr = 0.0f;
    if (x >= 2) {
        int q = p - 1;
        float a0 = n0[q], a1 = n1[q], a2 = n2[q];
        float Anum = gx(x - 2);                      // abc(-1,0) A-grid at col x-1
        float num = abc_dot(Anum, By, a0, a1, a2);   // ABC_left(y,x-1)
        float den = abc_dot(Ax,   By, a0, a1, a2);   // ABC_right(y,x-1)
        if (den != 0.0f) zr = (num / den) * d[p - 2];
    }

    o[0 * HW] = zu;
    o[1 * HW] = zd;
    o[2 * HW] = zl;
    o[3 * HW] = zr;
}

extern "C" void kernel_launch(void* const* d_in, const int* in_sizes, int n_in,
                              void* d_out, int out_size, void* d_ws, size_t ws_size,
                              hipStream_t stream) {
    const float* depth  = (const float*)d_in[0];
    const float* normal = (const float*)d_in[1];
    float* out = (float*)d_out;
    int total = B * HW;
    int block = 256;
    int grid = (total + block - 1) / block;
    znext_kernel<<<grid, block, 0, stream>>>(depth, normal, out);
}

// Round 7
// 53.339 us; speedup vs baseline: 1.9439x; 1.9439x over previous
//
#include <hip/hip_runtime.h>

typedef float v4f __attribute__((ext_vector_type(4)));

namespace {
constexpr int H = 480, W = 640, B = 32;
constexpr int HW = H * W;
constexpr int W4 = W / 4;                 // 160 float4 chunks per row
constexpr int BLOCK = 256;
constexpr int NWG = B * H * W4 / BLOCK;   // 9600
constexpr int PER_XCD = NWG / 8;          // 1200 (9600 % 8 == 0 -> bijective)
constexpr float CXf = 313.04f, CYf = 238.44f;
constexpr float RCPX = 1.0f / 582.62f;    // XLA div->mul-by-reciprocal (verified bit-exact)
constexpr float RCPY = 1.0f / 582.69f;
}

// Exact IEEE f32 mul/add, contraction-proof (inline asm is opaque to FMA fusion).
__device__ __forceinline__ float fmul_ieee(float a, float b) {
    float r; asm("v_mul_f32 %0, %1, %2" : "=v"(r) : "v"(a), "v"(b)); return r;
}
__device__ __forceinline__ float fadd_ieee(float a, float b) {
    float r; asm("v_add_f32 %0, %1, %2" : "=v"(r) : "v"(a), "v"(b)); return r;
}
// ((A*n0) + (B*n1)) + n2 -- sequential f32, no FMA (matches ref bit-exactly, R6).
__device__ __forceinline__ float abc_dot(float A, float Bv, float a0, float a1, float a2) {
    return fadd_ieee(fadd_ieee(fmul_ieee(A, a0), fmul_ieee(Bv, a1)), a2);
}
__device__ __forceinline__ float gx(int i) { return fmul_ieee((float)i - CXf, RCPX); }
__device__ __forceinline__ float gy(int i) { return fmul_ieee((float)i - CYf, RCPY); }

__device__ __forceinline__ void ld4(const float* p, float* a) {
    v4f v = *reinterpret_cast<const v4f*>(p);
    a[0] = v.x; a[1] = v.y; a[2] = v.z; a[3] = v.w;
}

__global__ __launch_bounds__(BLOCK) void znext_kernel(
    const float* __restrict__ depth,
    const float* __restrict__ normal,
    float* __restrict__ out)
{
    int bid = blockIdx.x;
    // XCD-chunked swizzle: XCD k (bid%8) owns contiguous chunk range -> vertical
    // neighbor rows are same-L2 hits instead of cross-XCD re-fetches.
    int wg = (bid & 7) * PER_XCD + (bid >> 3);
    int cid = wg * BLOCK + (int)threadIdx.x;
    int b = cid / (H * W4);
    int r = cid - b * (H * W4);
    int y = r / W4;
    int x0 = (r - y * W4) * 4;

    const float* d  = depth + (size_t)b * HW;
    const float* n0 = normal + (size_t)b * 3 * HW;
    const float* n1 = n0 + HW;
    const float* n2 = n1 + HW;

    int rowY = y * W;
    int rU  = min(y + 1, H - 1) * W;   // clamped: values unused when out of range
    int rD  = max(y - 1, 0) * W;
    int rU2 = min(y + 2, H - 1) * W;
    int rD2 = max(y - 2, 0) * W;

    float nU[3][4], nD[3][4], nY[3][4];
    ld4(n0 + rU + x0, nU[0]); ld4(n1 + rU + x0, nU[1]); ld4(n2 + rU + x0, nU[2]);
    ld4(n0 + rD + x0, nD[0]); ld4(n1 + rD + x0, nD[1]); ld4(n2 + rD + x0, nD[2]);
    ld4(n0 + rowY + x0, nY[0]); ld4(n1 + rowY + x0, nY[1]); ld4(n2 + rowY + x0, nY[2]);
    float dU[4], dD[4], dY[4];
    ld4(d + rU2 + x0, dU); ld4(d + rD2 + x0, dD); ld4(d + rowY + x0, dY);

    // clamped scalar edge loads (clamped values are never selected)
    int xm1 = max(x0 - 1, 0), xm2 = max(x0 - 2, 0);
    int xp4 = min(x0 + 4, W - 1), xp5 = min(x0 + 5, W - 1);
    float nL0 = n0[rowY + xm1], nL1 = n1[rowY + xm1], nL2 = n2[rowY + xm1];
    float nR0 = n0[rowY + xp4], nR1 = n1[rowY + xp4], nR2 = n2[rowY + xp4];
    float dm2 = d[rowY + xm2], dm1 = d[rowY + xm1];
    float dp4 = d[rowY + xp4], dp5 = d[rowY + xp5];

    float By  = gy(y);
    float BnU = gy(y + 2);
    float BnD = gy(y - 2);
    bool okU = (y < H - 2), okD = (y >= 2);

    float zu[4], zd[4], zl[4], zr[4];
#pragma unroll
    for (int j = 0; j < 4; ++j) {
        int x = x0 + j;
        float Ax = gx(x);
        // z_o_up = safe_div(ABC_down, ABC_up)(y+1,x) * depth[y+2][x]
        {
            float num = abc_dot(Ax, BnU, nU[0][j], nU[1][j], nU[2][j]);
            float den = abc_dot(Ax, By,  nU[0][j], nU[1][j], nU[2][j]);
            zu[j] = (okU && den != 0.0f) ? (num / den) * dU[j] : 0.0f;
        }
        // z_o_down = safe_div(ABC_up, ABC_down)(y-1,x) * depth[y-2][x]
        {
            float num = abc_dot(Ax, BnD, nD[0][j], nD[1][j], nD[2][j]);
            float den = abc_dot(Ax, By,  nD[0][j], nD[1][j], nD[2][j]);
            zd[j] = (okD && den != 0.0f) ? (num / den) * dD[j] : 0.0f;
        }
        // z_o_left = safe_div(ABC_right, ABC_left)(y,x+1) * depth[y][x+2]
        {
            float a0 = (j < 3) ? nY[0][j + 1] : nR0;
            float a1 = (j < 3) ? nY[1][j + 1] : nR1;
            float a2 = (j < 3) ? nY[2][j + 1] : nR2;
            float dd = (j < 2) ? dY[j + 2] : ((j == 2) ? dp4 : dp5);
            float num = abc_dot(gx(x + 2), By, a0, a1, a2);
            float den = abc_dot(Ax,        By, a0, a1, a2);
            zl[j] = ((x < W - 2) && den != 0.0f) ? (num / den) * dd : 0.0f;
        }
        // z_o_right = safe_div(ABC_left, ABC_right)(y,x-1) * depth[y][x-2]
        {
            float a0 = (j > 0) ? nY[0][j - 1] : nL0;
            float a1 = (j > 0) ? nY[1][j - 1] : nL1;
            float a2 = (j > 0) ? nY[2][j - 1] : nL2;
            float dd = (j >= 2) ? dY[j - 2] : ((j == 0) ? dm2 : dm1);
            float num = abc_dot(gx(x - 2), By, a0, a1, a2);
            float den = abc_dot(Ax,        By, a0, a1, a2);
            zr[j] = ((x >= 2) && den != 0.0f) ? (num / den) * dd : 0.0f;
        }
    }

    float* o = out + (size_t)b * 4 * HW + rowY + x0;
    v4f vu = { zu[0], zu[1], zu[2], zu[3] };
    v4f vd = { zd[0], zd[1], zd[2], zd[3] };
    v4f vl = { zl[0], zl[1], zl[2], zl[3] };
    v4f vr = { zr[0], zr[1], zr[2], zr[3] };
    // nontemporal: keep the 157 MB write stream out of L2, preserve it for input reuse
    __builtin_nontemporal_store(vu, reinterpret_cast<v4f*>(o));
    __builtin_nontemporal_store(vd, reinterpret_cast<v4f*>(o + HW));
    __builtin_nontemporal_store(vl, reinterpret_cast<v4f*>(o + 2 * HW));
    __builtin_nontemporal_store(vr, reinterpret_cast<v4f*>(o + 3 * HW));
}

extern "C" void kernel_launch(void* const* d_in, const int* in_sizes, int n_in,
                              void* d_out, int out_size, void* d_ws, size_t ws_size,
                              hipStream_t stream) {
    const float* depth  = (const float*)d_in[0];
    const float* normal = (const float*)d_in[1];
    float* out = (float*)d_out;
    znext_kernel<<<NWG, BLOCK, 0, stream>>>(depth, normal, out);
}

// Round 8
// 52.134 us; speedup vs baseline: 1.9888x; 1.0231x over previous
//
#include <hip/hip_runtime.h>

typedef float v4f __attribute__((ext_vector_type(4)));

namespace {
constexpr int H = 480, W = 640, B = 32;
constexpr int HW = H * W;
constexpr int W4 = W / 4;                 // 160 float4 chunks per row
constexpr int BLOCK = 256;
constexpr int NWG = B * H * W4 / BLOCK;   // 9600
constexpr int PER_XCD = NWG / 8;          // 1200 (9600 % 8 == 0 -> bijective)
constexpr float CXf = 313.04f, CYf = 238.44f;
constexpr float RCPX = 1.0f / 582.62f;    // XLA div->mul-by-reciprocal (verified bit-exact R6)
constexpr float RCPY = 1.0f / 582.69f;
}

// Exact IEEE f32 mul/add, contraction-proof (inline asm is opaque to FMA fusion).
__device__ __forceinline__ float fmul_ieee(float a, float b) {
    float r; asm("v_mul_f32 %0, %1, %2" : "=v"(r) : "v"(a), "v"(b)); return r;
}
__device__ __forceinline__ float fadd_ieee(float a, float b) {
    float r; asm("v_add_f32 %0, %1, %2" : "=v"(r) : "v"(a), "v"(b)); return r;
}
// ((A*n0) + (B*n1)) + n2 -- sequential f32, no FMA (bit-exact den/num, verified R6/R7).
__device__ __forceinline__ float abc_dot(float A, float Bv, float a0, float a1, float a2) {
    return fadd_ieee(fadd_ieee(fmul_ieee(A, a0), fmul_ieee(Bv, a1)), a2);
}
__device__ __forceinline__ float gx(int i) { return fmul_ieee((float)i - CXf, RCPX); }
__device__ __forceinline__ float gy(int i) { return fmul_ieee((float)i - CYf, RCPY); }

// Fast ratio: num * v_rcp_f32(den). ~2-3 ulp relative error on the ratio;
// max |out| ~7.5e4 -> abs err ~0.03 << threshold 1505. (Denominator stays bit-exact --
// that's where the 1e8x cancellation amplification lives; division is benign.)
__device__ __forceinline__ float fast_ratio(float num, float den) {
    return num * __builtin_amdgcn_rcpf(den);
}

__device__ __forceinline__ void ld4(const float* p, float* a) {
    v4f v = *reinterpret_cast<const v4f*>(p);
    a[0] = v.x; a[1] = v.y; a[2] = v.z; a[3] = v.w;
}

__global__ __launch_bounds__(BLOCK) void znext_kernel(
    const float* __restrict__ depth,
    const float* __restrict__ normal,
    float* __restrict__ out)
{
    int bid = blockIdx.x;
    // XCD-chunked swizzle: XCD k (bid%8) owns a contiguous chunk range -> vertical
    // neighbor rows are same-L2/L3 hits instead of cross-XCD re-fetches.
    int wg = (bid & 7) * PER_XCD + (bid >> 3);
    int cid = wg * BLOCK + (int)threadIdx.x;
    int b = cid / (H * W4);
    int r = cid - b * (H * W4);
    int y = r / W4;
    int x0 = (r - y * W4) * 4;

    const float* d  = depth + (size_t)b * HW;
    const float* n0 = normal + (size_t)b * 3 * HW;
    const float* n1 = n0 + HW;
    const float* n2 = n1 + HW;

    int rowY = y * W;
    int rU  = min(y + 1, H - 1) * W;   // clamped: values unused when out of range
    int rD  = max(y - 1, 0) * W;
    int rU2 = min(y + 2, H - 1) * W;
    int rD2 = max(y - 2, 0) * W;

    float nU[3][4], nD[3][4], nY[3][4];
    ld4(n0 + rU + x0, nU[0]); ld4(n1 + rU + x0, nU[1]); ld4(n2 + rU + x0, nU[2]);
    ld4(n0 + rD + x0, nD[0]); ld4(n1 + rD + x0, nD[1]); ld4(n2 + rD + x0, nD[2]);
    ld4(n0 + rowY + x0, nY[0]); ld4(n1 + rowY + x0, nY[1]); ld4(n2 + rowY + x0, nY[2]);
    float dU[4], dD[4], dY[4];
    ld4(d + rU2 + x0, dU); ld4(d + rD2 + x0, dD); ld4(d + rowY + x0, dY);

    // clamped scalar edge loads (clamped values are never selected)
    int xm1 = max(x0 - 1, 0), xm2 = max(x0 - 2, 0);
    int xp4 = min(x0 + 4, W - 1), xp5 = min(x0 + 5, W - 1);
    float nL0 = n0[rowY + xm1], nL1 = n1[rowY + xm1], nL2 = n2[rowY + xm1];
    float nR0 = n0[rowY + xp4], nR1 = n1[rowY + xp4], nR2 = n2[rowY + xp4];
    float dm2 = d[rowY + xm2], dm1 = d[rowY + xm1];
    float dp4 = d[rowY + xp4], dp5 = d[rowY + xp5];

    float By  = gy(y);
    float BnU = gy(y + 2);
    float BnD = gy(y - 2);
    bool okU = (y < H - 2), okD = (y >= 2);

    float zu[4], zd[4], zl[4], zr[4];
#pragma unroll
    for (int j = 0; j < 4; ++j) {
        int x = x0 + j;
        float Ax = gx(x);
        // z_o_up = safe_div(ABC_down, ABC_up)(y+1,x) * depth[y+2][x]
        {
            float num = abc_dot(Ax, BnU, nU[0][j], nU[1][j], nU[2][j]);
            float den = abc_dot(Ax, By,  nU[0][j], nU[1][j], nU[2][j]);
            zu[j] = (okU && den != 0.0f) ? fast_ratio(num, den) * dU[j] : 0.0f;
        }
        // z_o_down = safe_div(ABC_up, ABC_down)(y-1,x) * depth[y-2][x]
        {
            float num = abc_dot(Ax, BnD, nD[0][j], nD[1][j], nD[2][j]);
            float den = abc_dot(Ax, By,  nD[0][j], nD[1][j], nD[2][j]);
            zd[j] = (okD && den != 0.0f) ? fast_ratio(num, den) * dD[j] : 0.0f;
        }
        // z_o_left = safe_div(ABC_right, ABC_left)(y,x+1) * depth[y][x+2]
        {
            float a0 = (j < 3) ? nY[0][j + 1] : nR0;
            float a1 = (j < 3) ? nY[1][j + 1] : nR1;
            float a2 = (j < 3) ? nY[2][j + 1] : nR2;
            float dd = (j < 2) ? dY[j + 2] : ((j == 2) ? dp4 : dp5);
            float num = abc_dot(gx(x + 2), By, a0, a1, a2);
            float den = abc_dot(Ax,        By, a0, a1, a2);
            zl[j] = ((x < W - 2) && den != 0.0f) ? fast_ratio(num, den) * dd : 0.0f;
        }
        // z_o_right = safe_div(ABC_left, ABC_right)(y,x-1) * depth[y][x-2]
        {
            float a0 = (j > 0) ? nY[0][j - 1] : nL0;
            float a1 = (j > 0) ? nY[1][j - 1] : nL1;
            float a2 = (j > 0) ? nY[2][j - 1] : nL2;
            float dd = (j >= 2) ? dY[j - 2] : ((j == 0) ? dm2 : dm1);
            float num = abc_dot(gx(x - 2), By, a0, a1, a2);
            float den = abc_dot(Ax,        By, a0, a1, a2);
            zr[j] = ((x >= 2) && den != 0.0f) ? fast_ratio(num, den) * dd : 0.0f;
        }
    }

    float* o = out + (size_t)b * 4 * HW + rowY + x0;
    v4f vu = { zu[0], zu[1], zu[2], zu[3] };
    v4f vd = { zd[0], zd[1], zd[2], zd[3] };
    v4f vl = { zl[0], zl[1], zl[2], zl[3] };
    v4f vr = { zr[0], zr[1], zr[2], zr[3] };
    // nontemporal: keep the 157 MB write stream out of cache, preserve it for inputs
    __builtin_nontemporal_store(vu, reinterpret_cast<v4f*>(o));
    __builtin_nontemporal_store(vd, reinterpret_cast<v4f*>(o + HW));
    __builtin_nontemporal_store(vl, reinterpret_cast<v4f*>(o + 2 * HW));
    __builtin_nontemporal_store(vr, reinterpret_cast<v4f*>(o + 3 * HW));
}

extern "C" void kernel_launch(void* const* d_in, const int* in_sizes, int n_in,
                              void* d_out, int out_size, void* d_ws, size_t ws_size,
                              hipStream_t stream) {
    const float* depth  = (const float*)d_in[0];
    const float* normal = (const float*)d_in[1];
    float* out = (float*)d_out;
    znext_kernel<<<NWG, BLOCK, 0, stream>>>(depth, normal, out);
}